// Round 5
// baseline (160.349 us; speedup 1.0000x reference)
//
#include <hip/hip_runtime.h>

#define B_ 4
#define C_ 256
#define N_ 4096

typedef unsigned short u16;
typedef unsigned char u8;
typedef __bf16 bf16x8 __attribute__((ext_vector_type(8)));
typedef float f32x4 __attribute__((ext_vector_type(4)));
typedef float f32x16 __attribute__((ext_vector_type(16)));
typedef u16 u16x8 __attribute__((ext_vector_type(8)));
typedef u16 u16x4 __attribute__((ext_vector_type(4)));
typedef u8 u8x16 __attribute__((ext_vector_type(16)));
typedef int i32x4 __attribute__((ext_vector_type(4)));
typedef int i32x8 __attribute__((ext_vector_type(8)));

union BF8 { u16x8 u; bf16x8 b; };

__device__ __forceinline__ u16 f2bf(float f) {  // RNE
  unsigned int u = __float_as_uint(f);
  u += 0x7fffu + ((u >> 16) & 1u);
  return (u16)(u >> 16);
}
__device__ __forceinline__ u16 f2bf_fast(float f) {  // round-half-up
  return (u16)((__float_as_uint(f) + 0x8000u) >> 16);
}
__device__ __forceinline__ float bf2f(u16 u) {
  return __uint_as_float(((unsigned int)u) << 16);
}

__device__ __forceinline__ f32x16 mfma32(bf16x8 a, bf16x8 b, f32x16 c) {
  return __builtin_amdgcn_mfma_f32_32x32x16_bf16(a, b, c, 0, 0, 0);
}
// block-scaled fp8 MFMA, K=64, unit scales (e8m0 127 = 2^0): numerically
// identical to non-scaled fp8 but ~2.1x the MFMA rate.
__device__ __forceinline__ f32x16 mfma_sc64(i32x8 a, i32x8 b, f32x16 c) {
  return __builtin_amdgcn_mfma_scale_f32_32x32x64_f8f6f4(
      a, b, c, 0 /*A=fp8*/, 0 /*B=fp8*/, 0, 0x7f7f7f7f, 0, 0x7f7f7f7f);
}

// async global->LDS, 16B/lane, dest = wave-uniform base + lane*16
__device__ __forceinline__ void gl_lds16(const u8* g, u8* l) {
  __builtin_amdgcn_global_load_lds(
      (const __attribute__((address_space(1))) unsigned int*)g,
      (__attribute__((address_space(3))) unsigned int*)l, 16, 0, 0);
}

#define ROWMAP(r, half) (((r) & 3) + 8 * ((r) >> 2) + 4 * (half))

// sqrt((1/16)*log2e): folded into BOTH q and k -> softmax is bare exp2,
// and fp8 values sit in e4m3 normal range.
#define QK_SCALE 0.30028063f

// ---------------- weights fp32 -> bf16 fragment-order (once, tiny) ---------
// Wf[g = o/32][ks 0..15][lane 0..63][8 u16], lane=(half<<5)|l32 holds
// W[o = g*32+l32][k = ks*16 + half*8 .. +8]. Consumers load 1 KB contiguous
// per (g,ks) instead of 32 scattered 64B lines.
__global__ __launch_bounds__(256) void k_prep(const float* __restrict__ wq,
                                              const float* __restrict__ wo,
                                              u16* __restrict__ Wqb,
                                              u16* __restrict__ Wob) {
  int i = blockIdx.x * 256 + threadIdx.x;  // 32768 = (384+128) gk * 64 lanes
  int lane = i & 63;
  int gk = i >> 6;  // g*16+ks: 0..383 -> Wqb, 384..511 -> Wob
  int l32 = lane & 31, half = lane >> 5;
  const float* src;
  u16* dst;
  if (gk < 384) {
    int o = (gk >> 4) * 32 + l32, k = (gk & 15) * 16 + half * 8;
    src = wq + (size_t)o * C_ + k;
    dst = Wqb + ((size_t)gk * 64 + lane) * 8;
  } else {
    int gk2 = gk - 384;
    int o = (gk2 >> 4) * 32 + l32, k = (gk2 & 15) * 16 + half * 8;
    src = wo + (size_t)o * C_ + k;
    dst = Wob + ((size_t)gk2 * 64 + lane) * 8;
  }
  f32x4 v0 = *(const f32x4*)src;
  f32x4 v1 = *(const f32x4*)(src + 4);
  u16x8 r = {f2bf(v0[0]), f2bf(v0[1]), f2bf(v0[2]), f2bf(v0[3]),
             f2bf(v1[0]), f2bf(v1[1]), f2bf(v1[2]), f2bf(v1[3])};
  *(u16x8*)dst = r;
}

// ---------------- QKV projection -> fp8 Q/K/V, coalesced stores -------------
// grid (64 n0, 2 yb, 4 b). Weight fragments coalesced (fragment-order Wqb).
// x staged via 4x4 register micro-transpose. Results staged fp8 in LDS,
// stored as 128B lines (Q/K) / 64B sectors (V).
__global__ __launch_bounds__(256, 2) void k_qkv(
    const u16* __restrict__ Wqb, const float* __restrict__ bias,
    const float* __restrict__ x, u8* __restrict__ Qt, u8* __restrict__ Kt,
    u8* __restrict__ Vn) {
  __shared__ u16 Xs[64 * 264];
  __shared__ u8 Sg[9216];  // SQ: [64 pix][136] or SV: [128 c][72]
  const int b = blockIdx.z, yb = blockIdx.y, n0 = blockIdx.x * 64;
  const int t = threadIdx.x, w = t >> 6, lane = t & 63;
  const int l32 = lane & 31, half = lane >> 5;

  // x tile [256 c][64 n] f32 -> Xs[n][c] bf16, 4x4 register micro-transpose
#pragma unroll
  for (int it = 0; it < 4; ++it) {
    int chunk = t + 256 * it;  // 0..1023
    int cq = chunk >> 4;       // 0..63: c-quad
    int nq = chunk & 15;       // 0..15: n-quad
    f32x4 r[4];
#pragma unroll
    for (int j = 0; j < 4; ++j)
      r[j] = *(const f32x4*)(x +
                             (((size_t)b * C_ + cq * 4 + j) * N_ + n0 + nq * 4));
#pragma unroll
    for (int i = 0; i < 4; ++i) {
      u16x4 col = {f2bf(r[0][i]), f2bf(r[1][i]), f2bf(r[2][i]), f2bf(r[3][i])};
      *(u16x4*)&Xs[(nq * 4 + i) * 264 + cq * 4] = col;
    }
  }
  __syncthreads();

  BF8 xf[2][16];
#pragma unroll
  for (int nt = 0; nt < 2; ++nt)
#pragma unroll
    for (int ks = 0; ks < 16; ++ks)
      xf[nt][ks].u =
          *(const u16x8*)&Xs[(nt * 32 + l32) * 264 + ks * 16 + half * 8];

#pragma unroll
  for (int mt = 0; mt < 3; ++mt) {
    const int omr = yb * 384 + mt * 128;  // 128-wide tile, uniform seg
    const int seg = omr >> 8;             // 0=Q 1=K 2=V
    const int ow = omr + w * 32;          // this wave's 32 outputs
    BF8 wf[16];
    const u16* wrow = Wqb + ((size_t)((omr >> 5) + w) * 16 * 64 + lane) * 8;
#pragma unroll
    for (int ks = 0; ks < 16; ++ks)
      wf[ks].u = *(const u16x8*)(wrow + (size_t)ks * 64 * 8);

    f32x16 a0, a1;
#pragma unroll
    for (int r = 0; r < 16; ++r) a0[r] = a1[r] = 0.f;

    if (seg < 2) {
      // A = wf (m=o), B = xf (n=pix): regs -> o = ow+ROWMAP, lane -> pix
#pragma unroll
      for (int ks = 0; ks < 16; ++ks) {
        a0 = mfma32(wf[ks].b, xf[0][ks].b, a0);
        a1 = mfma32(wf[ks].b, xf[1][ks].b, a1);
      }
#pragma unroll
      for (int nt = 0; nt < 2; ++nt) {
        const f32x16& a = nt ? a1 : a0;
#pragma unroll
        for (int g = 0; g < 4; ++g) {
          f32x4 bv = *(const f32x4*)&bias[ow + 8 * g + 4 * half];
          float v0 = (a[4 * g + 0] + bv[0]) * QK_SCALE;
          float v1 = (a[4 * g + 1] + bv[1]) * QK_SCALE;
          float v2 = (a[4 * g + 2] + bv[2]) * QK_SCALE;
          float v3 = (a[4 * g + 3] + bv[3]) * QK_SCALE;
          int pkw = __builtin_amdgcn_cvt_pk_fp8_f32(v0, v1, 0, false);
          pkw = __builtin_amdgcn_cvt_pk_fp8_f32(v2, v3, pkw, true);
          *(int*)&Sg[(nt * 32 + l32) * 136 + w * 32 + 8 * g + 4 * half] = pkw;
        }
      }
      __syncthreads();
      {  // full-128B-line stores: Qt/Kt[b][pix][ol..ol+128)
        u8* dst = ((seg == 0) ? Qt : Kt) + ((size_t)b * N_ + n0) * C_ +
                  (omr & 255);
        int row = t >> 2, cb = t & 3;
        u8x16 q0 = *(const u8x16*)&Sg[row * 136 + cb * 32];
        u8x16 q1 = *(const u8x16*)&Sg[row * 136 + cb * 32 + 16];
        u8* d = dst + (size_t)row * C_ + cb * 32;
        *(u8x16*)d = q0;
        *(u8x16*)(d + 16) = q1;
      }
      __syncthreads();
    } else {
      // A = xf (m=pix), B = wf (n=c): regs -> pix = ROWMAP, lane -> c
#pragma unroll
      for (int ks = 0; ks < 16; ++ks) {
        a0 = mfma32(xf[0][ks].b, wf[ks].b, a0);
        a1 = mfma32(xf[1][ks].b, wf[ks].b, a1);
      }
      const float bvv = bias[ow + l32];
#pragma unroll
      for (int nt = 0; nt < 2; ++nt) {
        const f32x16& a = nt ? a1 : a0;
#pragma unroll
        for (int g = 0; g < 4; ++g) {
          float v0 = a[4 * g + 0] + bvv, v1 = a[4 * g + 1] + bvv;
          float v2 = a[4 * g + 2] + bvv, v3 = a[4 * g + 3] + bvv;
          int pkw = __builtin_amdgcn_cvt_pk_fp8_f32(v0, v1, 0, false);
          pkw = __builtin_amdgcn_cvt_pk_fp8_f32(v2, v3, pkw, true);
          *(int*)&Sg[(w * 32 + l32) * 72 + nt * 32 + 8 * g + 4 * half] = pkw;
        }
      }
      __syncthreads();
      {  // Vn[b][c][n0..n0+64): 64B sectors
        u8* dst = Vn + ((size_t)b * C_ + (omr - 512)) * N_ + n0;
        int row = t >> 1, ch = t & 1;
        u8x16 q0 = *(const u8x16*)&Sg[row * 72 + ch * 32];
        u8x16 q1 = *(const u8x16*)&Sg[row * 72 + ch * 32 + 16];
        u8* d = dst + (size_t)row * N_ + ch * 32;
        *(u8x16*)d = q0;
        *(u8x16*)(d + 16) = q1;
      }
      __syncthreads();
    }
  }
}

// ---------------- out-proj + 4-plane combine + bias + residual --------------
__global__ __launch_bounds__(256, 2) void k_out(
    const u16* __restrict__ Wob, const float* __restrict__ bias,
    const float* __restrict__ xres, float* __restrict__ outp,
    const u16* __restrict__ Op, const float* __restrict__ Ml) {
  __shared__ u16 Xs[32 * 264];
  const int b = blockIdx.y, n0 = blockIdx.x * 32;
  const int t = threadIdx.x, w = t >> 6, lane = t & 63;
  const int l32 = lane & 31, half = lane >> 5;
  const size_t TEN = (size_t)B_ * N_ * C_;
  const size_t BN = (size_t)B_ * N_;
#pragma unroll
  for (int it = 0; it < 4; ++it) {
    int chunk = t + 256 * it;
    int row = chunk >> 5, col = chunk & 31;
    size_t rowg = (size_t)b * N_ + n0 + row;
    float s = 0.f;
#pragma unroll
    for (int p = 0; p < 8; ++p) s += Ml[p * BN + rowg];
    float f = 1.0f / s;
    size_t base = rowg * C_ + col * 8;
    u16x8 a0 = *(const u16x8*)&Op[base];
    u16x8 a1 = *(const u16x8*)&Op[TEN + base];
    u16x8 a2 = *(const u16x8*)&Op[2 * TEN + base];
    u16x8 a3 = *(const u16x8*)&Op[3 * TEN + base];
    u16x8 rr;
#pragma unroll
    for (int i = 0; i < 8; ++i)
      rr[i] = f2bf((bf2f(a0[i]) + bf2f(a1[i]) + bf2f(a2[i]) + bf2f(a3[i])) * f);
    *(u16x8*)&Xs[row * 264 + col * 8] = rr;
  }
  __syncthreads();

  BF8 xf[16];
#pragma unroll
  for (int ks = 0; ks < 16; ++ks)
    xf[ks].u = *(const u16x8*)&Xs[l32 * 264 + ks * 16 + half * 8];

#pragma unroll
  for (int mt = 0; mt < 2; ++mt) {
    const int om = w * 64 + mt * 32;
    BF8 wf[16];
    const u16* wrow = Wob + ((size_t)(w * 2 + mt) * 16 * 64 + lane) * 8;
#pragma unroll
    for (int ks = 0; ks < 16; ++ks)
      wf[ks].u = *(const u16x8*)(wrow + (size_t)ks * 64 * 8);
    f32x16 a;
#pragma unroll
    for (int r = 0; r < 16; ++r) a[r] = 0.f;
#pragma unroll
    for (int ks = 0; ks < 16; ++ks) a = mfma32(wf[ks].b, xf[ks].b, a);
#pragma unroll
    for (int r = 0; r < 16; ++r) {
      int oc = om + ROWMAP(r, half);
      size_t idx = ((size_t)b * C_ + oc) * N_ + n0 + l32;
      outp[idx] = a[r] + bias[oc] + xres[idx];
    }
  }
}

// ---------------- flash attention: scaled fp8 MFMA QK^T and PV.
// grid 1024 = 4b x 4jq x 64 q-tiles (j range split in quarters for TLP:
// 1024 blocks @ 52 KB LDS -> 3 blocks/CU resident vs 2 before).
// LDS 53248: K dbuf @0/16384, V single @32768, P @49152 [2 mh][32 px][64B].
// V single-buffered: V(t+1) staged at BOTTOM of iter t (after the barrier
// that proves PV(t) reads done); before PV(t): s_waitcnt vmcnt(4) retires
// the 4 V loads, leaves the 4 K prefetches in flight (counted vmcnt, T4).
// Swizzle keys ((row>>1)^(row>>3))&3 on V and P spread former 4-way quads.
__global__ __launch_bounds__(256, 3) void k_attn(const u8* __restrict__ Qt,
                                                 const u8* __restrict__ Kt,
                                                 const u8* __restrict__ Vn,
                                                 u16* __restrict__ Op,
                                                 float* __restrict__ Ml) {
  __shared__ u8 raw[53248];
  const int id = blockIdx.x;
  const int b = (id & 7) >> 1;
  const int jq = (id & 1) | (((id >> 3) & 1) << 1);
  const int i0 = (id >> 4) * 64;
  const int t = threadIdx.x, w = t >> 6, lane = t & 63;
  const int l32 = lane & 31, half = lane >> 5;
  const int mh = w >> 1, hh = w & 1;

  // Q fragment for scaled K=64 MFMA: lane holds k = half*32 + [0,32) of each
  // 64-wide k-block kb.
  i32x8 qf8[4];
  {
    const u8* qrow =
        Qt + ((size_t)b * N_ + i0 + mh * 32 + l32) * C_ + half * 32;
#pragma unroll
    for (int kb = 0; kb < 4; ++kb) {
      i32x4 r0 = *(const i32x4*)(qrow + kb * 64);
      i32x4 r1 = *(const i32x4*)(qrow + kb * 64 + 16);
      qf8[kb] = __builtin_shufflevector(r0, r1, 0, 1, 2, 3, 4, 5, 6, 7);
    }
  }
  f32x16 o[4];  // channels hh*128 + ct*32 + ROWMAP(r,half), pixel mh*32+l32
#pragma unroll
  for (int ct = 0; ct < 4; ++ct)
#pragma unroll
    for (int r = 0; r < 16; ++r) o[ct][r] = 0.f;
  float l_i = 0.f;

  const u8* kbase = Kt + (size_t)b * N_ * C_;
  const u8* vbase = Vn + (size_t)b * (size_t)C_ * N_;
  const int jbeg = jq * (N_ / 4), jend = jbeg + N_ / 4;

  const int kR = lane >> 4, kG = lane & 15;  // K: 4 rows/call, granule
  const int vR = lane >> 2, vG = lane & 3;   // V: 16 rows/call, granule

  // Hoisted per-lane staging pointers (swizzles j0-invariant).
  const u8* kpr = kbase + (size_t)(jbeg + w * 16 + kR) * C_;
  const u8* vpr = vbase + (size_t)(w * 64 + vR) * N_ + jbeg;
  int ksw[4];
#pragma unroll
  for (int it = 0; it < 4; ++it)
    ksw[it] = it * 4 * C_ + ((kG ^ ((it * 4 + kR) & 15)) << 4);
  int vsw[4];
#pragma unroll
  for (int it = 0; it < 4; ++it)
    vsw[it] = it * 16 * N_ +
              ((vG ^ (((vR >> 1) ^ (it * 2 + (vR >> 3))) & 3)) << 4);

  auto kstage = [&](int buf) {
#pragma unroll
    for (int it = 0; it < 4; ++it)
      gl_lds16(kpr + ksw[it], raw + buf * 16384 + (w * 16 + it * 4) * 256);
  };
  auto vstage = [&]() {
#pragma unroll
    for (int it = 0; it < 4; ++it)
      gl_lds16(vpr + vsw[it], raw + 32768 + (w * 64 + it * 16) * 64);
  };

  vstage();      // V(0)
  kstage(0);     // K(0)
  kpr += 64 * C_;
  vpr += 64;
  __syncthreads();
  int cur = 0;

  const int jrow = hh * 32 + l32;  // K row whose S this wave computes
  const int rx = (jrow & 15) << 4;
  const int pm = ((l32 >> 1) ^ (l32 >> 3)) & 3;   // P granule swizzle key
  const int vrk = ((l32 >> 1) ^ (l32 >> 3)) & 3;  // V read swizzle key
  u8* Pl = raw + 49152 + mh * 2048 + l32 * 64;    // P row for this pixel

  for (int j0 = jbeg; j0 < jend; j0 += 64) {
    if (j0 + 64 >= jend) kpr -= (size_t)(N_ / 4) * C_;  // dummy wrap
    kstage(cur ^ 1);
    kpr += 64 * C_;

    // S^T 32x32: lane = pixel l32, regs -> j-local = 32hh + 8g+4half+i
    f32x16 s;
#pragma unroll
    for (int r = 0; r < 16; ++r) s[r] = 0.f;
    {
      const u8* krowp = raw + cur * 16384 + jrow * 256;
      __builtin_amdgcn_s_setprio(1);
#pragma unroll
      for (int kb = 0; kb < 4; ++kb) {
        const int base = kb * 64 + half * 32;
        i32x4 r0 = *(const i32x4*)(krowp + (base ^ rx));
        i32x4 r1 = *(const i32x4*)(krowp + ((base + 16) ^ rx));
        i32x8 kf8 = __builtin_shufflevector(r0, r1, 0, 1, 2, 3, 4, 5, 6, 7);
        s = mfma_sc64(kf8, qf8[kb], s);
      }
      __builtin_amdgcn_s_setprio(0);
    }

    // p = exp2(s) -> fp8 dwords, published to P LDS (granule XOR pm).
    float tile_sum = 0.f;
#pragma unroll
    for (int g = 0; g < 4; ++g) {
      float p0 = __builtin_amdgcn_exp2f(s[4 * g + 0]);
      float p1 = __builtin_amdgcn_exp2f(s[4 * g + 1]);
      float p2 = __builtin_amdgcn_exp2f(s[4 * g + 2]);
      float p3 = __builtin_amdgcn_exp2f(s[4 * g + 3]);
      tile_sum += (p0 + p1) + (p2 + p3);
      int w0 = __builtin_amdgcn_cvt_pk_fp8_f32(p0, p1, 0, false);
      int pkw = __builtin_amdgcn_cvt_pk_fp8_f32(p2, p3, w0, true);
      int adr = (((2 * hh + (g >> 1)) ^ pm) << 4) + (2 * (g & 1) + half) * 4;
      *(int*)(Pl + adr) = pkw;
    }
    tile_sum += __shfl_xor(tile_sum, 32);
    l_i += tile_sum;

    // Wait V(t) (4 oldest vmem) + publish P; K(t+1) stays in flight.
    __builtin_amdgcn_sched_barrier(0);
    asm volatile("s_waitcnt vmcnt(4) lgkmcnt(0)\n\ts_barrier" ::: "memory");
    __builtin_amdgcn_sched_barrier(0);

    // PV: o[ct] over FULL 64 j, channels hh*128 + ct*32 + *.
    {
      i32x4 p0 = *(const i32x4*)(Pl + (((2 * half + 0) ^ pm) << 4));
      i32x4 p1 = *(const i32x4*)(Pl + (((2 * half + 1) ^ pm) << 4));
      i32x8 pf = __builtin_shufflevector(p0, p1, 0, 1, 2, 3, 4, 5, 6, 7);
      const u8* vbp = raw + 32768 + (hh * 128 + l32) * 64;
      __builtin_amdgcn_s_setprio(1);
#pragma unroll
      for (int ct = 0; ct < 4; ++ct) {
        const u8* vrowp = vbp + ct * 32 * 64;
        i32x4 v0 = *(const i32x4*)(vrowp + (((2 * half + 0) ^ vrk) << 4));
        i32x4 v1 = *(const i32x4*)(vrowp + (((2 * half + 1) ^ vrk) << 4));
        i32x8 vf = __builtin_shufflevector(v0, v1, 0, 1, 2, 3, 4, 5, 6, 7);
        o[ct] = mfma_sc64(vf, pf, o[ct]);
      }
      __builtin_amdgcn_s_setprio(0);
    }

    __syncthreads();  // drains vmem (K(t+1) done) + PV reads done -> V free
    cur ^= 1;
    if (j0 + 64 < jend) {  // stage V(t+1); skipped on last iter (epilogue
      vstage();            // reuses raw -> no post-barrier writes allowed)
      vpr += 64;
    }
  }

  // ---- epilogue: each (px,c) owned by exactly one wave -> no merge.
  float* ml = Ml + ((size_t)(jq * 2 + hh) * B_ + b) * N_;
  if (lane < 32) ml[i0 + mh * 32 + l32] = l_i;

  u16* M = (u16*)raw;  // [64][264]
#pragma unroll
  for (int ct = 0; ct < 4; ++ct)
#pragma unroll
    for (int g = 0; g < 4; ++g) {
      u16x4 pkv = {f2bf_fast(o[ct][4 * g + 0]), f2bf_fast(o[ct][4 * g + 1]),
                   f2bf_fast(o[ct][4 * g + 2]), f2bf_fast(o[ct][4 * g + 3])};
      *(u16x4*)&M[(mh * 32 + l32) * 264 + hh * 128 + ct * 32 + 8 * g +
                  4 * half] = pkv;
    }
  __syncthreads();

  u16* op = Op + ((size_t)jq * B_ + b) * (size_t)N_ * C_ + (size_t)i0 * C_;
  const int row = t >> 2, cb = t & 3;
#pragma unroll
  for (int k = 0; k < 8; ++k) {
    u16x8 m0 = *(const u16x8*)&M[row * 264 + cb * 64 + k * 8];
    *(u16x8*)&op[(size_t)row * C_ + cb * 64 + k * 8] = m0;
  }
}

extern "C" void kernel_launch(void* const* d_in, const int* in_sizes, int n_in,
                              void* d_out, int out_size, void* d_ws,
                              size_t ws_size, hipStream_t stream) {
  (void)in_sizes; (void)n_in; (void)out_size; (void)ws_size;
  const float* x = (const float*)d_in[0];
  const float* w_qkv = (const float*)d_in[1];
  const float* b_qkv = (const float*)d_in[2];
  const float* w_out = (const float*)d_in[3];
  const float* b_out = (const float*)d_in[4];
  float* outp = (float*)d_out;

  const size_t TENS = (size_t)B_ * N_ * C_;  // 4M elems
  u8* Qt = (u8*)d_ws;        // [B][N][C] fp8 (scaled)      4 MB
  u8* Kt = Qt + TENS;        // [B][N][C] fp8 (scaled)      4 MB
  u8* Vn = Kt + TENS;        // [B][C][N] fp8               4 MB
  u16* Op = (u16*)(Vn + TENS);  // [4][B][N][C] bf16       32 MB
  float* Ml = (float*)(Op + 4 * TENS);          // [8][B][N]  512 KB
  u16* Wqb = (u16*)(Ml + 8 * (size_t)B_ * N_);  // [3C][C]    384 KB
  u16* Wob = Wqb + 3 * C_ * C_;                 // [C][C]     128 KB

  k_prep<<<dim3(128), 256, 0, stream>>>(w_qkv, w_out, Wqb, Wob);
  k_qkv<<<dim3(64, 2, 4), 256, 0, stream>>>(Wqb, b_qkv, x, Qt, Kt, Vn);
  k_attn<<<dim3(1024), 256, 0, stream>>>(Qt, Kt, Vn, Op, Ml);
  k_out<<<dim3(128, 4), 256, 0, stream>>>(Wob, b_out, x, outp, Op, Ml);
}

// Round 6
// 142.817 us; speedup vs baseline: 1.1228x; 1.1228x over previous
//
#include <hip/hip_runtime.h>

#define B_ 4
#define C_ 256
#define N_ 4096

typedef unsigned short u16;
typedef unsigned char u8;
typedef __bf16 bf16x8 __attribute__((ext_vector_type(8)));
typedef float f32x4 __attribute__((ext_vector_type(4)));
typedef float f32x16 __attribute__((ext_vector_type(16)));
typedef u16 u16x8 __attribute__((ext_vector_type(8)));
typedef u16 u16x4 __attribute__((ext_vector_type(4)));
typedef u8 u8x16 __attribute__((ext_vector_type(16)));
typedef int i32x4 __attribute__((ext_vector_type(4)));
typedef int i32x8 __attribute__((ext_vector_type(8)));

union BF8 { u16x8 u; bf16x8 b; };

__device__ __forceinline__ u16 f2bf(float f) {  // RNE
  unsigned int u = __float_as_uint(f);
  u += 0x7fffu + ((u >> 16) & 1u);
  return (u16)(u >> 16);
}
__device__ __forceinline__ u16 f2bf_fast(float f) {  // round-half-up
  return (u16)((__float_as_uint(f) + 0x8000u) >> 16);
}
__device__ __forceinline__ float bf2f(u16 u) {
  return __uint_as_float(((unsigned int)u) << 16);
}

__device__ __forceinline__ f32x16 mfma32(bf16x8 a, bf16x8 b, f32x16 c) {
  return __builtin_amdgcn_mfma_f32_32x32x16_bf16(a, b, c, 0, 0, 0);
}
// block-scaled fp8 MFMA, K=64, unit scales (e8m0 127 = 2^0): numerically
// identical to non-scaled fp8 but ~2.1x the MFMA rate.
__device__ __forceinline__ f32x16 mfma_sc64(i32x8 a, i32x8 b, f32x16 c) {
  return __builtin_amdgcn_mfma_scale_f32_32x32x64_f8f6f4(
      a, b, c, 0 /*A=fp8*/, 0 /*B=fp8*/, 0, 0x7f7f7f7f, 0, 0x7f7f7f7f);
}

// async global->LDS, 16B/lane, dest = wave-uniform base + lane*16
__device__ __forceinline__ void gl_lds16(const u8* g, u8* l) {
  __builtin_amdgcn_global_load_lds(
      (const __attribute__((address_space(1))) unsigned int*)g,
      (__attribute__((address_space(3))) unsigned int*)l, 16, 0, 0);
}

#define ROWMAP(r, half) (((r) & 3) + 8 * ((r) >> 2) + 4 * (half))

// sqrt((1/16)*log2e): folded into BOTH q and k -> softmax is bare exp2,
// and fp8 values sit in e4m3 normal range.
#define QK_SCALE 0.30028063f

// ---------------- weights fp32 -> bf16 fragment-order (once, tiny) ---------
// Wf[g = o/32][ks 0..15][lane 0..63][8 u16], lane=(half<<5)|l32 holds
// W[o = g*32+l32][k = ks*16 + half*8 .. +8]. Consumers load 1 KB contiguous
// per (g,ks) instead of 32 scattered 64B lines.
__global__ __launch_bounds__(256) void k_prep(const float* __restrict__ wq,
                                              const float* __restrict__ wo,
                                              u16* __restrict__ Wqb,
                                              u16* __restrict__ Wob) {
  int i = blockIdx.x * 256 + threadIdx.x;  // 32768 = (384+128) gk * 64 lanes
  int lane = i & 63;
  int gk = i >> 6;  // g*16+ks: 0..383 -> Wqb, 384..511 -> Wob
  int l32 = lane & 31, half = lane >> 5;
  const float* src;
  u16* dst;
  if (gk < 384) {
    int o = (gk >> 4) * 32 + l32, k = (gk & 15) * 16 + half * 8;
    src = wq + (size_t)o * C_ + k;
    dst = Wqb + ((size_t)gk * 64 + lane) * 8;
  } else {
    int gk2 = gk - 384;
    int o = (gk2 >> 4) * 32 + l32, k = (gk2 & 15) * 16 + half * 8;
    src = wo + (size_t)o * C_ + k;
    dst = Wob + ((size_t)gk2 * 64 + lane) * 8;
  }
  f32x4 v0 = *(const f32x4*)src;
  f32x4 v1 = *(const f32x4*)(src + 4);
  u16x8 r = {f2bf(v0[0]), f2bf(v0[1]), f2bf(v0[2]), f2bf(v0[3]),
             f2bf(v1[0]), f2bf(v1[1]), f2bf(v1[2]), f2bf(v1[3])};
  *(u16x8*)dst = r;
}

// ---------------- QKV projection -> fp8 Q/K/V, coalesced stores -------------
// grid (64 n0, 2 yb, 4 b). Weight fragments coalesced (fragment-order Wqb).
// x staged via 4x4 register micro-transpose. Results staged fp8 in LDS,
// stored as 128B lines (Q/K) / 64B sectors (V).
__global__ __launch_bounds__(256, 2) void k_qkv(
    const u16* __restrict__ Wqb, const float* __restrict__ bias,
    const float* __restrict__ x, u8* __restrict__ Qt, u8* __restrict__ Kt,
    u8* __restrict__ Vn) {
  __shared__ u16 Xs[64 * 264];
  __shared__ u8 Sg[9216];  // SQ: [64 pix][136] or SV: [128 c][72]
  const int b = blockIdx.z, yb = blockIdx.y, n0 = blockIdx.x * 64;
  const int t = threadIdx.x, w = t >> 6, lane = t & 63;
  const int l32 = lane & 31, half = lane >> 5;

  // x tile [256 c][64 n] f32 -> Xs[n][c] bf16, 4x4 register micro-transpose
#pragma unroll
  for (int it = 0; it < 4; ++it) {
    int chunk = t + 256 * it;  // 0..1023
    int cq = chunk >> 4;       // 0..63: c-quad
    int nq = chunk & 15;       // 0..15: n-quad
    f32x4 r[4];
#pragma unroll
    for (int j = 0; j < 4; ++j)
      r[j] = *(const f32x4*)(x +
                             (((size_t)b * C_ + cq * 4 + j) * N_ + n0 + nq * 4));
#pragma unroll
    for (int i = 0; i < 4; ++i) {
      u16x4 col = {f2bf(r[0][i]), f2bf(r[1][i]), f2bf(r[2][i]), f2bf(r[3][i])};
      *(u16x4*)&Xs[(nq * 4 + i) * 264 + cq * 4] = col;
    }
  }
  __syncthreads();

  BF8 xf[2][16];
#pragma unroll
  for (int nt = 0; nt < 2; ++nt)
#pragma unroll
    for (int ks = 0; ks < 16; ++ks)
      xf[nt][ks].u =
          *(const u16x8*)&Xs[(nt * 32 + l32) * 264 + ks * 16 + half * 8];

#pragma unroll
  for (int mt = 0; mt < 3; ++mt) {
    const int omr = yb * 384 + mt * 128;  // 128-wide tile, uniform seg
    const int seg = omr >> 8;             // 0=Q 1=K 2=V
    const int ow = omr + w * 32;          // this wave's 32 outputs
    BF8 wf[16];
    const u16* wrow = Wqb + ((size_t)((omr >> 5) + w) * 16 * 64 + lane) * 8;
#pragma unroll
    for (int ks = 0; ks < 16; ++ks)
      wf[ks].u = *(const u16x8*)(wrow + (size_t)ks * 64 * 8);

    f32x16 a0, a1;
#pragma unroll
    for (int r = 0; r < 16; ++r) a0[r] = a1[r] = 0.f;

    if (seg < 2) {
      // A = wf (m=o), B = xf (n=pix): regs -> o = ow+ROWMAP, lane -> pix
#pragma unroll
      for (int ks = 0; ks < 16; ++ks) {
        a0 = mfma32(wf[ks].b, xf[0][ks].b, a0);
        a1 = mfma32(wf[ks].b, xf[1][ks].b, a1);
      }
#pragma unroll
      for (int nt = 0; nt < 2; ++nt) {
        const f32x16& a = nt ? a1 : a0;
#pragma unroll
        for (int g = 0; g < 4; ++g) {
          f32x4 bv = *(const f32x4*)&bias[ow + 8 * g + 4 * half];
          float v0 = (a[4 * g + 0] + bv[0]) * QK_SCALE;
          float v1 = (a[4 * g + 1] + bv[1]) * QK_SCALE;
          float v2 = (a[4 * g + 2] + bv[2]) * QK_SCALE;
          float v3 = (a[4 * g + 3] + bv[3]) * QK_SCALE;
          int pkw = __builtin_amdgcn_cvt_pk_fp8_f32(v0, v1, 0, false);
          pkw = __builtin_amdgcn_cvt_pk_fp8_f32(v2, v3, pkw, true);
          *(int*)&Sg[(nt * 32 + l32) * 136 + w * 32 + 8 * g + 4 * half] = pkw;
        }
      }
      __syncthreads();
      {  // full-128B-line stores: Qt/Kt[b][pix][ol..ol+128)
        u8* dst = ((seg == 0) ? Qt : Kt) + ((size_t)b * N_ + n0) * C_ +
                  (omr & 255);
        int row = t >> 2, cb = t & 3;
        u8x16 q0 = *(const u8x16*)&Sg[row * 136 + cb * 32];
        u8x16 q1 = *(const u8x16*)&Sg[row * 136 + cb * 32 + 16];
        u8* d = dst + (size_t)row * C_ + cb * 32;
        *(u8x16*)d = q0;
        *(u8x16*)(d + 16) = q1;
      }
      __syncthreads();
    } else {
      // A = xf (m=pix), B = wf (n=c): regs -> pix = ROWMAP, lane -> c
#pragma unroll
      for (int ks = 0; ks < 16; ++ks) {
        a0 = mfma32(xf[0][ks].b, wf[ks].b, a0);
        a1 = mfma32(xf[1][ks].b, wf[ks].b, a1);
      }
      const float bvv = bias[ow + l32];
#pragma unroll
      for (int nt = 0; nt < 2; ++nt) {
        const f32x16& a = nt ? a1 : a0;
#pragma unroll
        for (int g = 0; g < 4; ++g) {
          float v0 = a[4 * g + 0] + bvv, v1 = a[4 * g + 1] + bvv;
          float v2 = a[4 * g + 2] + bvv, v3 = a[4 * g + 3] + bvv;
          int pkw = __builtin_amdgcn_cvt_pk_fp8_f32(v0, v1, 0, false);
          pkw = __builtin_amdgcn_cvt_pk_fp8_f32(v2, v3, pkw, true);
          *(int*)&Sg[(w * 32 + l32) * 72 + nt * 32 + 8 * g + 4 * half] = pkw;
        }
      }
      __syncthreads();
      {  // Vn[b][c][n0..n0+64): 64B sectors
        u8* dst = Vn + ((size_t)b * C_ + (omr - 512)) * N_ + n0;
        int row = t >> 1, ch = t & 1;
        u8x16 q0 = *(const u8x16*)&Sg[row * 72 + ch * 32];
        u8x16 q1 = *(const u8x16*)&Sg[row * 72 + ch * 32 + 16];
        u8* d = dst + (size_t)row * N_ + ch * 32;
        *(u8x16*)d = q0;
        *(u8x16*)(d + 16) = q1;
      }
      __syncthreads();
    }
  }
}

// ---------------- out-proj + split-combine + bias + residual ----------------
__global__ __launch_bounds__(256, 2) void k_out(
    const u16* __restrict__ Wob, const float* __restrict__ bias,
    const float* __restrict__ xres, float* __restrict__ outp,
    const u16* __restrict__ Op, const float* __restrict__ Ml) {
  __shared__ u16 Xs[32 * 264];
  const int b = blockIdx.y, n0 = blockIdx.x * 32;
  const int t = threadIdx.x, w = t >> 6, lane = t & 63;
  const int l32 = lane & 31, half = lane >> 5;
  const size_t TEN = (size_t)B_ * N_ * C_;
  const size_t BN = (size_t)B_ * N_;
#pragma unroll
  for (int it = 0; it < 4; ++it) {
    int chunk = t + 256 * it;
    int row = chunk >> 5, col = chunk & 31;
    size_t rowg = (size_t)b * N_ + n0 + row;
    float f = 1.0f / (Ml[rowg] + Ml[BN + rowg] + Ml[2 * BN + rowg] +
                      Ml[3 * BN + rowg]);
    size_t base = rowg * C_ + col * 8;
    u16x8 a0 = *(const u16x8*)&Op[base];
    u16x8 a1 = *(const u16x8*)&Op[TEN + base];
    u16x8 rr;
#pragma unroll
    for (int i = 0; i < 8; ++i) rr[i] = f2bf((bf2f(a0[i]) + bf2f(a1[i])) * f);
    *(u16x8*)&Xs[row * 264 + col * 8] = rr;
  }
  __syncthreads();

  BF8 xf[16];
#pragma unroll
  for (int ks = 0; ks < 16; ++ks)
    xf[ks].u = *(const u16x8*)&Xs[l32 * 264 + ks * 16 + half * 8];

#pragma unroll
  for (int mt = 0; mt < 2; ++mt) {
    const int om = w * 64 + mt * 32;
    BF8 wf[16];
    const u16* wrow = Wob + ((size_t)(w * 2 + mt) * 16 * 64 + lane) * 8;
#pragma unroll
    for (int ks = 0; ks < 16; ++ks)
      wf[ks].u = *(const u16x8*)(wrow + (size_t)ks * 64 * 8);
    f32x16 a;
#pragma unroll
    for (int r = 0; r < 16; ++r) a[r] = 0.f;
#pragma unroll
    for (int ks = 0; ks < 16; ++ks) a = mfma32(wf[ks].b, xf[ks].b, a);
#pragma unroll
    for (int r = 0; r < 16; ++r) {
      int oc = om + ROWMAP(r, half);
      size_t idx = ((size_t)b * C_ + oc) * N_ + n0 + l32;
      outp[idx] = a[r] + bias[oc] + xres[idx];
    }
  }
}

// ---------------- flash attention: scaled fp8 MFMA for BOTH QK^T and PV.
// R4 structure (512 blocks, jh halves, K+V double-buffered, 1 vm-drain
// barrier/iter + 1 lgkm-only mid-iter barrier) with the R5-proven swizzle
// keys ((row>>1)^(row>>3))&3 on V and P (bank conflicts 7.54M -> 4.59M).
// raw: K[2]@0/16384, V[2]@32768/49152, P@65536 [2 mh][32 px][64B].
__global__ __launch_bounds__(256, 2) void k_attn(const u8* __restrict__ Qt,
                                                 const u8* __restrict__ Kt,
                                                 const u8* __restrict__ Vn,
                                                 u16* __restrict__ Op,
                                                 float* __restrict__ Ml) {
  __shared__ u8 raw[69632];
  const int id = blockIdx.x;
  const int xcd = id & 7;
  const int b = xcd >> 1;
  const int jh = xcd & 1;
  const int i0 = (id >> 3) * 64;
  const int t = threadIdx.x, w = t >> 6, lane = t & 63;
  const int l32 = lane & 31, half = lane >> 5;
  const int mh = w >> 1, hh = w & 1;

  // Q fragment for scaled K=64 MFMA: lane holds k = half*32 + [0,32) of each
  // 64-wide k-block kb.
  i32x8 qf8[4];
  {
    const u8* qrow =
        Qt + ((size_t)b * N_ + i0 + mh * 32 + l32) * C_ + half * 32;
#pragma unroll
    for (int kb = 0; kb < 4; ++kb) {
      i32x4 r0 = *(const i32x4*)(qrow + kb * 64);
      i32x4 r1 = *(const i32x4*)(qrow + kb * 64 + 16);
      qf8[kb] = __builtin_shufflevector(r0, r1, 0, 1, 2, 3, 4, 5, 6, 7);
    }
  }
  f32x16 o[4];  // channels hh*128 + ct*32 + ROWMAP(r,half), pixel mh*32+l32
#pragma unroll
  for (int ct = 0; ct < 4; ++ct)
#pragma unroll
    for (int r = 0; r < 16; ++r) o[ct][r] = 0.f;
  float l_i = 0.f;

  const u8* kbase = Kt + (size_t)b * N_ * C_;
  const u8* vbase = Vn + (size_t)b * (size_t)C_ * N_;
  const int jbeg = jh * (N_ / 2), jend = jbeg + N_ / 2;

  const int kR = lane >> 4, kG = lane & 15;  // K: 4 rows/call, granule
  const int vR = lane >> 2, vG = lane & 3;   // V: 16 rows/call, granule

  // Hoisted per-lane staging pointers (swizzles j0-invariant).
  const u8* kpr = kbase + (size_t)(jbeg + w * 16 + kR) * C_;
  const u8* vpr = vbase + (size_t)(w * 64 + vR) * N_ + jbeg;
  int ksw[4];
#pragma unroll
  for (int it = 0; it < 4; ++it)
    ksw[it] = it * 4 * C_ + ((kG ^ ((it * 4 + kR) & 15)) << 4);
  // V write swizzle for row c = w*64+it*16+vR: key = ((c>>1)^(c>>3))&3
  //   = ((vR>>1) ^ (2*it + (vR>>3))) & 3  (w terms vanish mod 4).
  int vsw[4];
#pragma unroll
  for (int it = 0; it < 4; ++it)
    vsw[it] = it * 16 * N_ +
              ((vG ^ (((vR >> 1) ^ (it * 2 + (vR >> 3))) & 3)) << 4);

  auto stage = [&](int buf) {
#pragma unroll
    for (int it = 0; it < 4; ++it)
      gl_lds16(kpr + ksw[it], raw + buf * 16384 + (w * 16 + it * 4) * 256);
#pragma unroll
    for (int it = 0; it < 4; ++it)
      gl_lds16(vpr + vsw[it],
               raw + 32768 + buf * 16384 + (w * 64 + it * 16) * 64);
  };

  stage(0);
  kpr += 64 * C_;
  vpr += 64;
  __syncthreads();
  int cur = 0;

  const int jrow = hh * 32 + l32;  // K row whose S this wave computes
  const int rx = (jrow & 15) << 4;
  const int pm = ((l32 >> 1) ^ (l32 >> 3)) & 3;   // P granule swizzle key
  const int vrk = ((l32 >> 1) ^ (l32 >> 3)) & 3;  // V read swizzle key
  u8* Pl = raw + 65536 + mh * 2048 + l32 * 64;    // P row for this pixel

  for (int j0 = jbeg; j0 < jend; j0 += 64) {
    if (j0 + 64 >= jend) {  // last iter: dummy (valid) prefetch of jbeg
      kpr -= (size_t)(N_ / 2) * C_;
      vpr -= N_ / 2;
    }
    stage(cur ^ 1);
    kpr += 64 * C_;
    vpr += 64;

    // S^T 32x32: lane = pixel l32, regs -> j-local = 32hh + 8g+4half+i
    f32x16 s;
#pragma unroll
    for (int r = 0; r < 16; ++r) s[r] = 0.f;
    {
      const u8* krowp = raw + cur * 16384 + jrow * 256;
      __builtin_amdgcn_s_setprio(1);
#pragma unroll
      for (int kb = 0; kb < 4; ++kb) {
        const int base = kb * 64 + half * 32;
        i32x4 r0 = *(const i32x4*)(krowp + (base ^ rx));
        i32x4 r1 = *(const i32x4*)(krowp + ((base + 16) ^ rx));
        i32x8 kf8 = __builtin_shufflevector(r0, r1, 0, 1, 2, 3, 4, 5, 6, 7);
        s = mfma_sc64(kf8, qf8[kb], s);
      }
      __builtin_amdgcn_s_setprio(0);
    }

    // p = exp2(s) -> fp8 dwords, published to P LDS (granule XOR pm).
    float tile_sum = 0.f;
#pragma unroll
    for (int g = 0; g < 4; ++g) {
      float p0 = __builtin_amdgcn_exp2f(s[4 * g + 0]);
      float p1 = __builtin_amdgcn_exp2f(s[4 * g + 1]);
      float p2 = __builtin_amdgcn_exp2f(s[4 * g + 2]);
      float p3 = __builtin_amdgcn_exp2f(s[4 * g + 3]);
      tile_sum += (p0 + p1) + (p2 + p3);
      int w0 = __builtin_amdgcn_cvt_pk_fp8_f32(p0, p1, 0, false);
      int pkw = __builtin_amdgcn_cvt_pk_fp8_f32(p2, p3, w0, true);
      int adr = (((2 * hh + (g >> 1)) ^ pm) << 4) + (2 * (g & 1) + half) * 4;
      *(int*)(Pl + adr) = pkw;
    }
    tile_sum += __shfl_xor(tile_sum, 32);
    l_i += tile_sum;

    // publish P across the mh wave-pair: lgkm-only barrier (the staged
    // global_load_lds prefetch must NOT be drained here).
    __builtin_amdgcn_sched_barrier(0);
    asm volatile("s_waitcnt lgkmcnt(0)\n\ts_barrier" ::: "memory");
    __builtin_amdgcn_sched_barrier(0);

    // PV: o[ct] over FULL 64 j, channels hh*128 + ct*32 + *.
    {
      i32x4 p0 = *(const i32x4*)(Pl + (((2 * half + 0) ^ pm) << 4));
      i32x4 p1 = *(const i32x4*)(Pl + (((2 * half + 1) ^ pm) << 4));
      i32x8 pf = __builtin_shufflevector(p0, p1, 0, 1, 2, 3, 4, 5, 6, 7);
      const u8* vbp = raw + 32768 + cur * 16384 + (hh * 128 + l32) * 64;
      __builtin_amdgcn_s_setprio(1);
#pragma unroll
      for (int ct = 0; ct < 4; ++ct) {
        const u8* vrowp = vbp + ct * 32 * 64;
        i32x4 v0 = *(const i32x4*)(vrowp + (((2 * half + 0) ^ vrk) << 4));
        i32x4 v1 = *(const i32x4*)(vrowp + (((2 * half + 1) ^ vrk) << 4));
        i32x8 vf = __builtin_shufflevector(v0, v1, 0, 1, 2, 3, 4, 5, 6, 7);
        o[ct] = mfma_sc64(vf, pf, o[ct]);
      }
      __builtin_amdgcn_s_setprio(0);
    }

    __syncthreads();  // drains global_load_lds (vmcnt) + all LDS reads done
    cur ^= 1;
  }

  // ---- epilogue: each (px,c) owned by exactly one wave -> no merge.
  float* ml = Ml + ((size_t)(jh * 2 + hh) * B_ + b) * N_;
  if (lane < 32) ml[i0 + mh * 32 + l32] = l_i;

  u16* M = (u16*)raw;  // [64][264]
#pragma unroll
  for (int ct = 0; ct < 4; ++ct)
#pragma unroll
    for (int g = 0; g < 4; ++g) {
      u16x4 pkv = {f2bf_fast(o[ct][4 * g + 0]), f2bf_fast(o[ct][4 * g + 1]),
                   f2bf_fast(o[ct][4 * g + 2]), f2bf_fast(o[ct][4 * g + 3])};
      *(u16x4*)&M[(mh * 32 + l32) * 264 + hh * 128 + ct * 32 + 8 * g +
                  4 * half] = pkv;
    }
  __syncthreads();

  u16* op = Op + ((size_t)jh * B_ + b) * (size_t)N_ * C_ + (size_t)i0 * C_;
  const int row = t >> 2, cb = t & 3;
#pragma unroll
  for (int k = 0; k < 8; ++k) {
    u16x8 m0 = *(const u16x8*)&M[row * 264 + cb * 64 + k * 8];
    *(u16x8*)&op[(size_t)row * C_ + cb * 64 + k * 8] = m0;
  }
}

extern "C" void kernel_launch(void* const* d_in, const int* in_sizes, int n_in,
                              void* d_out, int out_size, void* d_ws,
                              size_t ws_size, hipStream_t stream) {
  (void)in_sizes; (void)n_in; (void)out_size; (void)ws_size;
  const float* x = (const float*)d_in[0];
  const float* w_qkv = (const float*)d_in[1];
  const float* b_qkv = (const float*)d_in[2];
  const float* w_out = (const float*)d_in[3];
  const float* b_out = (const float*)d_in[4];
  float* outp = (float*)d_out;

  const size_t TENS = (size_t)B_ * N_ * C_;  // 4M elems
  u8* Qt = (u8*)d_ws;        // [B][N][C] fp8 (scaled)      4 MB
  u8* Kt = Qt + TENS;        // [B][N][C] fp8 (scaled)      4 MB
  u8* Vn = Kt + TENS;        // [B][C][N] fp8               4 MB
  u16* Op = (u16*)(Vn + TENS);  // [2][B][N][C] bf16       16 MB
  float* Ml = (float*)(Op + 2 * TENS);          // [4][B][N]  256 KB
  u16* Wqb = (u16*)(Ml + 4 * (size_t)B_ * N_);  // [3C][C]    384 KB
  u16* Wob = Wqb + 3 * C_ * C_;                 // [C][C]     128 KB

  k_prep<<<dim3(128), 256, 0, stream>>>(w_qkv, w_out, Wqb, Wob);
  k_qkv<<<dim3(64, 2, 4), 256, 0, stream>>>(Wqb, b_qkv, x, Qt, Kt, Vn);
  k_attn<<<dim3(512), 256, 0, stream>>>(Qt, Kt, Vn, Op, Ml);
  k_out<<<dim3(128, 4), 256, 0, stream>>>(Wob, b_out, x, outp, Op, Ml);
}

// Round 7
// 139.099 us; speedup vs baseline: 1.1528x; 1.0267x over previous
//
#include <hip/hip_runtime.h>

#define B_ 4
#define C_ 256
#define N_ 4096

typedef unsigned short u16;
typedef unsigned char u8;
typedef __bf16 bf16x8 __attribute__((ext_vector_type(8)));
typedef float f32x4 __attribute__((ext_vector_type(4)));
typedef float f32x16 __attribute__((ext_vector_type(16)));
typedef u16 u16x8 __attribute__((ext_vector_type(8)));
typedef u16 u16x4 __attribute__((ext_vector_type(4)));
typedef u8 u8x16 __attribute__((ext_vector_type(16)));
typedef int i32x4 __attribute__((ext_vector_type(4)));
typedef int i32x8 __attribute__((ext_vector_type(8)));

union BF8 { u16x8 u; bf16x8 b; };

__device__ __forceinline__ u16 f2bf(float f) {  // RNE
  unsigned int u = __float_as_uint(f);
  u += 0x7fffu + ((u >> 16) & 1u);
  return (u16)(u >> 16);
}
__device__ __forceinline__ u16 f2bf_fast(float f) {  // round-half-up
  return (u16)((__float_as_uint(f) + 0x8000u) >> 16);
}
__device__ __forceinline__ float bf2f(u16 u) {
  return __uint_as_float(((unsigned int)u) << 16);
}

__device__ __forceinline__ f32x16 mfma32(bf16x8 a, bf16x8 b, f32x16 c) {
  return __builtin_amdgcn_mfma_f32_32x32x16_bf16(a, b, c, 0, 0, 0);
}
// block-scaled fp8 MFMA, K=64, unit scales (e8m0 127 = 2^0): numerically
// identical to non-scaled fp8 but ~2.1x the MFMA rate.
__device__ __forceinline__ f32x16 mfma_sc64(i32x8 a, i32x8 b, f32x16 c) {
  return __builtin_amdgcn_mfma_scale_f32_32x32x64_f8f6f4(
      a, b, c, 0 /*A=fp8*/, 0 /*B=fp8*/, 0, 0x7f7f7f7f, 0, 0x7f7f7f7f);
}

// async global->LDS, 16B/lane, dest = wave-uniform base + lane*16
__device__ __forceinline__ void gl_lds16(const u8* g, u8* l) {
  __builtin_amdgcn_global_load_lds(
      (const __attribute__((address_space(1))) unsigned int*)g,
      (__attribute__((address_space(3))) unsigned int*)l, 16, 0, 0);
}

#define ROWMAP(r, half) (((r) & 3) + 8 * ((r) >> 2) + 4 * (half))

// sqrt((1/16)*log2e): folded into BOTH q and k -> softmax is bare exp2,
// and fp8 values sit in e4m3 normal range.
#define QK_SCALE 0.30028063f

// ---------------- weights fp32 -> bf16 fragment-order (once, tiny) ---------
__global__ __launch_bounds__(256) void k_prep(const float* __restrict__ wq,
                                              const float* __restrict__ wo,
                                              u16* __restrict__ Wqb,
                                              u16* __restrict__ Wob) {
  int i = blockIdx.x * 256 + threadIdx.x;  // 32768 = (384+128) gk * 64 lanes
  int lane = i & 63;
  int gk = i >> 6;  // g*16+ks: 0..383 -> Wqb, 384..511 -> Wob
  int l32 = lane & 31, half = lane >> 5;
  const float* src;
  u16* dst;
  if (gk < 384) {
    int o = (gk >> 4) * 32 + l32, k = (gk & 15) * 16 + half * 8;
    src = wq + (size_t)o * C_ + k;
    dst = Wqb + ((size_t)gk * 64 + lane) * 8;
  } else {
    int gk2 = gk - 384;
    int o = (gk2 >> 4) * 32 + l32, k = (gk2 & 15) * 16 + half * 8;
    src = wo + (size_t)o * C_ + k;
    dst = Wob + ((size_t)gk2 * 64 + lane) * 8;
  }
  f32x4 v0 = *(const f32x4*)src;
  f32x4 v1 = *(const f32x4*)(src + 4);
  u16x8 r = {f2bf(v0[0]), f2bf(v0[1]), f2bf(v0[2]), f2bf(v0[3]),
             f2bf(v1[0]), f2bf(v1[1]), f2bf(v1[2]), f2bf(v1[3])};
  *(u16x8*)dst = r;
}

// ---------------- QKV projection -> fp8 Q/K/V, coalesced stores -------------
__global__ __launch_bounds__(256, 2) void k_qkv(
    const u16* __restrict__ Wqb, const float* __restrict__ bias,
    const float* __restrict__ x, u8* __restrict__ Qt, u8* __restrict__ Kt,
    u8* __restrict__ Vn) {
  __shared__ u16 Xs[64 * 264];
  __shared__ u8 Sg[9216];  // SQ: [64 pix][136] or SV: [128 c][72]
  const int b = blockIdx.z, yb = blockIdx.y, n0 = blockIdx.x * 64;
  const int t = threadIdx.x, w = t >> 6, lane = t & 63;
  const int l32 = lane & 31, half = lane >> 5;

  // x tile [256 c][64 n] f32 -> Xs[n][c] bf16, 4x4 register micro-transpose
#pragma unroll
  for (int it = 0; it < 4; ++it) {
    int chunk = t + 256 * it;  // 0..1023
    int cq = chunk >> 4;       // 0..63: c-quad
    int nq = chunk & 15;       // 0..15: n-quad
    f32x4 r[4];
#pragma unroll
    for (int j = 0; j < 4; ++j)
      r[j] = *(const f32x4*)(x +
                             (((size_t)b * C_ + cq * 4 + j) * N_ + n0 + nq * 4));
#pragma unroll
    for (int i = 0; i < 4; ++i) {
      u16x4 col = {f2bf(r[0][i]), f2bf(r[1][i]), f2bf(r[2][i]), f2bf(r[3][i])};
      *(u16x4*)&Xs[(nq * 4 + i) * 264 + cq * 4] = col;
    }
  }
  __syncthreads();

  BF8 xf[2][16];
#pragma unroll
  for (int nt = 0; nt < 2; ++nt)
#pragma unroll
    for (int ks = 0; ks < 16; ++ks)
      xf[nt][ks].u =
          *(const u16x8*)&Xs[(nt * 32 + l32) * 264 + ks * 16 + half * 8];

#pragma unroll
  for (int mt = 0; mt < 3; ++mt) {
    const int omr = yb * 384 + mt * 128;  // 128-wide tile, uniform seg
    const int seg = omr >> 8;             // 0=Q 1=K 2=V
    const int ow = omr + w * 32;          // this wave's 32 outputs
    BF8 wf[16];
    const u16* wrow = Wqb + ((size_t)((omr >> 5) + w) * 16 * 64 + lane) * 8;
#pragma unroll
    for (int ks = 0; ks < 16; ++ks)
      wf[ks].u = *(const u16x8*)(wrow + (size_t)ks * 64 * 8);

    f32x16 a0, a1;
#pragma unroll
    for (int r = 0; r < 16; ++r) a0[r] = a1[r] = 0.f;

    if (seg < 2) {
      // A = wf (m=o), B = xf (n=pix): regs -> o = ow+ROWMAP, lane -> pix
#pragma unroll
      for (int ks = 0; ks < 16; ++ks) {
        a0 = mfma32(wf[ks].b, xf[0][ks].b, a0);
        a1 = mfma32(wf[ks].b, xf[1][ks].b, a1);
      }
#pragma unroll
      for (int nt = 0; nt < 2; ++nt) {
        const f32x16& a = nt ? a1 : a0;
#pragma unroll
        for (int g = 0; g < 4; ++g) {
          f32x4 bv = *(const f32x4*)&bias[ow + 8 * g + 4 * half];
          float v0 = (a[4 * g + 0] + bv[0]) * QK_SCALE;
          float v1 = (a[4 * g + 1] + bv[1]) * QK_SCALE;
          float v2 = (a[4 * g + 2] + bv[2]) * QK_SCALE;
          float v3 = (a[4 * g + 3] + bv[3]) * QK_SCALE;
          int pkw = __builtin_amdgcn_cvt_pk_fp8_f32(v0, v1, 0, false);
          pkw = __builtin_amdgcn_cvt_pk_fp8_f32(v2, v3, pkw, true);
          *(int*)&Sg[(nt * 32 + l32) * 136 + w * 32 + 8 * g + 4 * half] = pkw;
        }
      }
      __syncthreads();
      {  // full-128B-line stores: Qt/Kt[b][pix][ol..ol+128)
        u8* dst = ((seg == 0) ? Qt : Kt) + ((size_t)b * N_ + n0) * C_ +
                  (omr & 255);
        int row = t >> 2, cb = t & 3;
        u8x16 q0 = *(const u8x16*)&Sg[row * 136 + cb * 32];
        u8x16 q1 = *(const u8x16*)&Sg[row * 136 + cb * 32 + 16];
        u8* d = dst + (size_t)row * C_ + cb * 32;
        *(u8x16*)d = q0;
        *(u8x16*)(d + 16) = q1;
      }
      __syncthreads();
    } else {
      // A = xf (m=pix), B = wf (n=c): regs -> pix = ROWMAP, lane -> c
#pragma unroll
      for (int ks = 0; ks < 16; ++ks) {
        a0 = mfma32(xf[0][ks].b, wf[ks].b, a0);
        a1 = mfma32(xf[1][ks].b, wf[ks].b, a1);
      }
      const float bvv = bias[ow + l32];
#pragma unroll
      for (int nt = 0; nt < 2; ++nt) {
        const f32x16& a = nt ? a1 : a0;
#pragma unroll
        for (int g = 0; g < 4; ++g) {
          float v0 = a[4 * g + 0] + bvv, v1 = a[4 * g + 1] + bvv;
          float v2 = a[4 * g + 2] + bvv, v3 = a[4 * g + 3] + bvv;
          int pkw = __builtin_amdgcn_cvt_pk_fp8_f32(v0, v1, 0, false);
          pkw = __builtin_amdgcn_cvt_pk_fp8_f32(v2, v3, pkw, true);
          *(int*)&Sg[(w * 32 + l32) * 72 + nt * 32 + 8 * g + 4 * half] = pkw;
        }
      }
      __syncthreads();
      {  // Vn[b][c][n0..n0+64): 64B sectors
        u8* dst = Vn + ((size_t)b * C_ + (omr - 512)) * N_ + n0;
        int row = t >> 1, ch = t & 1;
        u8x16 q0 = *(const u8x16*)&Sg[row * 72 + ch * 32];
        u8x16 q1 = *(const u8x16*)&Sg[row * 72 + ch * 32 + 16];
        u8* d = dst + (size_t)row * N_ + ch * 32;
        *(u8x16*)d = q0;
        *(u8x16*)(d + 16) = q1;
      }
      __syncthreads();
    }
  }
}

// ---------------- out-proj + split-combine + bias + residual ----------------
__global__ __launch_bounds__(256, 2) void k_out(
    const u16* __restrict__ Wob, const float* __restrict__ bias,
    const float* __restrict__ xres, float* __restrict__ outp,
    const u16* __restrict__ Op, const float* __restrict__ Ml) {
  __shared__ u16 Xs[32 * 264];
  const int b = blockIdx.y, n0 = blockIdx.x * 32;
  const int t = threadIdx.x, w = t >> 6, lane = t & 63;
  const int l32 = lane & 31, half = lane >> 5;
  const size_t TEN = (size_t)B_ * N_ * C_;
  const size_t BN = (size_t)B_ * N_;
#pragma unroll
  for (int it = 0; it < 4; ++it) {
    int chunk = t + 256 * it;
    int row = chunk >> 5, col = chunk & 31;
    size_t rowg = (size_t)b * N_ + n0 + row;
    float f = 1.0f / (Ml[rowg] + Ml[BN + rowg] + Ml[2 * BN + rowg] +
                      Ml[3 * BN + rowg]);
    size_t base = rowg * C_ + col * 8;
    u16x8 a0 = *(const u16x8*)&Op[base];
    u16x8 a1 = *(const u16x8*)&Op[TEN + base];
    u16x8 rr;
#pragma unroll
    for (int i = 0; i < 8; ++i) rr[i] = f2bf((bf2f(a0[i]) + bf2f(a1[i])) * f);
    *(u16x8*)&Xs[row * 264 + col * 8] = rr;
  }
  __syncthreads();

  BF8 xf[16];
#pragma unroll
  for (int ks = 0; ks < 16; ++ks)
    xf[ks].u = *(const u16x8*)&Xs[l32 * 264 + ks * 16 + half * 8];

#pragma unroll
  for (int mt = 0; mt < 2; ++mt) {
    const int om = w * 64 + mt * 32;
    BF8 wf[16];
    const u16* wrow = Wob + ((size_t)(w * 2 + mt) * 16 * 64 + lane) * 8;
#pragma unroll
    for (int ks = 0; ks < 16; ++ks)
      wf[ks].u = *(const u16x8*)(wrow + (size_t)ks * 64 * 8);
    f32x16 a;
#pragma unroll
    for (int r = 0; r < 16; ++r) a[r] = 0.f;
#pragma unroll
    for (int ks = 0; ks < 16; ++ks) a = mfma32(wf[ks].b, xf[ks].b, a);
#pragma unroll
    for (int r = 0; r < 16; ++r) {
      int oc = om + ROWMAP(r, half);
      size_t idx = ((size_t)b * C_ + oc) * N_ + n0 + l32;
      outp[idx] = a[r] + bias[oc] + xres[idx];
    }
  }
}

// ---------------- flash attention: P-lagged pipeline, 8 waves / 128 px.
// Iter t: stage(t+1) || QK(t) || PV(t-1) in ONE barrier-free region, then
// softmax(t) + publish P(t) into opposite parity, then ONE __syncthreads.
// K dbuf 32K @0, V tri-buf 48K @32768, P dbuf 16K @81920 ([par][4mh][32][64B]).
// Waves (mh 0..3, hh 0..1): QK for (mh-pixels x hh-j-half); PV for
// (mh-pixels x hh-channel-half) over FULL 64 j of tile t-1.
// grid 256 = 4b x 2jh x 32 q-tiles of 128 px; 1 block/CU, 8 waves.
__global__ __launch_bounds__(512, 2) void k_attn(const u8* __restrict__ Qt,
                                                 const u8* __restrict__ Kt,
                                                 const u8* __restrict__ Vn,
                                                 u16* __restrict__ Op,
                                                 float* __restrict__ Ml) {
  __shared__ u8 raw[98304];
  const int id = blockIdx.x;
  const int xcd = id & 7;
  const int b = xcd >> 1;
  const int jh = xcd & 1;
  const int i0 = (id >> 3) * 128;
  const int t = threadIdx.x, w = t >> 6, lane = t & 63;
  const int l32 = lane & 31, half = lane >> 5;
  const int mh = w >> 1, hh = w & 1;

  // Q fragment: pixel row = i0 + mh*32 + l32; lane holds k = half*32+[0,32)
  i32x8 qf8[4];
  {
    const u8* qrow =
        Qt + ((size_t)b * N_ + i0 + mh * 32 + l32) * C_ + half * 32;
#pragma unroll
    for (int kb = 0; kb < 4; ++kb) {
      i32x4 r0 = *(const i32x4*)(qrow + kb * 64);
      i32x4 r1 = *(const i32x4*)(qrow + kb * 64 + 16);
      qf8[kb] = __builtin_shufflevector(r0, r1, 0, 1, 2, 3, 4, 5, 6, 7);
    }
  }
  f32x16 o[4];  // channels hh*128+ct*32+ROWMAP(r,half), pixel mh*32+l32
#pragma unroll
  for (int ct = 0; ct < 4; ++ct)
#pragma unroll
    for (int r = 0; r < 16; ++r) o[ct][r] = 0.f;
  float l_i = 0.f;

  const u8* kbase = Kt + (size_t)b * N_ * C_;
  const u8* vbase = Vn + (size_t)b * (size_t)C_ * N_;
  const int jbeg = jh * (N_ / 2);

  const int kR = lane >> 4, kG = lane & 15;  // K: 4 rows/wave/call
  const int vR = lane >> 2, vG = lane & 3;   // V: 16 rows/wave/call

  // Hoisted per-lane staging pointers; swizzle keys tile-invariant.
  const u8* kpr = kbase + (size_t)(jbeg + w * 4 + kR) * C_;
  const u8* vpr = vbase + (size_t)(w * 16 + vR) * N_ + jbeg;
  // K write row (per call it): it*32 + w*4 + kR; key = row & 15 (it-free).
  int ksw[2];
#pragma unroll
  for (int it = 0; it < 2; ++it)
    ksw[it] = it * 32 * C_ + ((kG ^ ((w * 4 + kR) & 15)) << 4);
  // V write row c = it*128 + w*16 + vR; key = ((c>>1)^(c>>3))&3 (it-free).
  const int vkey = ((vR >> 1) ^ (w * 2 + (vR >> 3))) & 3;
  int vsw[2];
#pragma unroll
  for (int it = 0; it < 2; ++it)
    vsw[it] = it * 128 * N_ + ((vG ^ vkey) << 4);

  auto stage = [&](int kb, int vs) {  // advances kpr/vpr by one 64-j tile
    gl_lds16(kpr + ksw[0], raw + kb + w * 1024);
    gl_lds16(kpr + ksw[1], raw + kb + 8192 + w * 1024);
    gl_lds16(vpr + vsw[0], raw + 32768 + vs + w * 1024);
    gl_lds16(vpr + vsw[1], raw + 32768 + vs + 8192 + w * 1024);
    kpr += 64 * C_;
    vpr += 64;
  };

  const int jrow = hh * 32 + l32;  // K row whose S this wave computes
  const int rx = (jrow & 15) << 4;
  const int pm = ((l32 >> 1) ^ (l32 >> 3)) & 3;  // P/V granule swizzle key
  u8* Prow = raw + 81920 + mh * 2048 + l32 * 64;  // + parity offset

  auto do_qk = [&](int kbr) {
    f32x16 s;
#pragma unroll
    for (int r = 0; r < 16; ++r) s[r] = 0.f;
    const u8* krowp = raw + kbr + jrow * 256;
    __builtin_amdgcn_s_setprio(1);
#pragma unroll
    for (int kb = 0; kb < 4; ++kb) {
      const int base = kb * 64 + half * 32;
      i32x4 r0 = *(const i32x4*)(krowp + (base ^ rx));
      i32x4 r1 = *(const i32x4*)(krowp + ((base + 16) ^ rx));
      i32x8 kf8 = __builtin_shufflevector(r0, r1, 0, 1, 2, 3, 4, 5, 6, 7);
      s = mfma_sc64(kf8, qf8[kb], s);
    }
    __builtin_amdgcn_s_setprio(0);
    return s;
  };
  auto do_softpub = [&](const f32x16& s, int pwr) {
    float tile_sum = 0.f;
#pragma unroll
    for (int g = 0; g < 4; ++g) {
      float p0 = __builtin_amdgcn_exp2f(s[4 * g + 0]);
      float p1 = __builtin_amdgcn_exp2f(s[4 * g + 1]);
      float p2 = __builtin_amdgcn_exp2f(s[4 * g + 2]);
      float p3 = __builtin_amdgcn_exp2f(s[4 * g + 3]);
      tile_sum += (p0 + p1) + (p2 + p3);
      int w0 = __builtin_amdgcn_cvt_pk_fp8_f32(p0, p1, 0, false);
      int pkw = __builtin_amdgcn_cvt_pk_fp8_f32(p2, p3, w0, true);
      int adr = (((2 * hh + (g >> 1)) ^ pm) << 4) + (2 * (g & 1) + half) * 4;
      *(int*)(Prow + pwr + adr) = pkw;
    }
    tile_sum += __shfl_xor(tile_sum, 32);
    l_i += tile_sum;
  };
  auto do_pv = [&](int prd, int vrd) {
    const u8* Pl = Prow + prd;
    i32x4 p0 = *(const i32x4*)(Pl + (((2 * half + 0) ^ pm) << 4));
    i32x4 p1 = *(const i32x4*)(Pl + (((2 * half + 1) ^ pm) << 4));
    i32x8 pf = __builtin_shufflevector(p0, p1, 0, 1, 2, 3, 4, 5, 6, 7);
    const u8* vbp = raw + 32768 + vrd + (hh * 128 + l32) * 64;
    __builtin_amdgcn_s_setprio(1);
#pragma unroll
    for (int ct = 0; ct < 4; ++ct) {
      const u8* vrowp = vbp + ct * 32 * 64;
      i32x4 v0 = *(const i32x4*)(vrowp + (((2 * half + 0) ^ pm) << 4));
      i32x4 v1 = *(const i32x4*)(vrowp + (((2 * half + 1) ^ pm) << 4));
      i32x8 vf = __builtin_shufflevector(v0, v1, 0, 1, 2, 3, 4, 5, 6, 7);
      o[ct] = mfma_sc64(vf, pf, o[ct]);
    }
    __builtin_amdgcn_s_setprio(0);
  };

  stage(0, 0);  // tile 0 -> kbuf0, vslot0
  __syncthreads();

  // prologue t=0 (no PV yet)
  stage(16384, 16384);  // tile 1 -> kbuf1, vslot1
  {
    f32x16 s = do_qk(0);
    do_softpub(s, 0);  // P(0) -> parity 0
  }
  __syncthreads();

  // steady state t=1..31: kbr=(t&1)*16K, vrd=((t-1)%3)*16K, vwr=((t+1)%3)*16K,
  // prd=((t-1)&1)*8K; publish into prd^8K.
  int kbr = 16384, vrd = 0, vwr = 32768, prd = 0;
  for (int it = 1; it < 32; ++it) {
    if (it < 31) stage(kbr ^ 16384, vwr);  // tile it+1
    f32x16 s = do_qk(kbr);
    do_pv(prd, vrd);
    do_softpub(s, prd ^ 8192);
    __syncthreads();
    kbr ^= 16384;
    prd ^= 8192;
    vrd = (vrd == 32768) ? 0 : vrd + 16384;
    vwr = (vwr == 32768) ? 0 : vwr + 16384;
  }
  // epilogue: drain PV(31) (prd/vrd already advanced to t=32 view)
  do_pv(prd, vrd);

  // ---- epilogue: each (px,c) owned by exactly one wave -> no merge.
  float* ml = Ml + ((size_t)(jh * 2 + hh) * B_ + b) * N_;
  if (lane < 32) ml[i0 + mh * 32 + l32] = l_i;
  __syncthreads();  // all PV reads done before raw reuse

  u16* M = (u16*)raw;  // [128][264]
#pragma unroll
  for (int ct = 0; ct < 4; ++ct)
#pragma unroll
    for (int g = 0; g < 4; ++g) {
      u16x4 pkv = {f2bf_fast(o[ct][4 * g + 0]), f2bf_fast(o[ct][4 * g + 1]),
                   f2bf_fast(o[ct][4 * g + 2]), f2bf_fast(o[ct][4 * g + 3])};
      *(u16x4*)&M[(mh * 32 + l32) * 264 + hh * 128 + ct * 32 + 8 * g +
                  4 * half] = pkv;
    }
  __syncthreads();

  u16* op = Op + ((size_t)jh * B_ + b) * (size_t)N_ * C_ + (size_t)i0 * C_;
  const int row = t >> 2, cb = t & 3;  // 512 threads: rows 0..127
#pragma unroll
  for (int k = 0; k < 8; ++k) {
    u16x8 m0 = *(const u16x8*)&M[row * 264 + cb * 64 + k * 8];
    *(u16x8*)&op[(size_t)row * C_ + cb * 64 + k * 8] = m0;
  }
}

extern "C" void kernel_launch(void* const* d_in, const int* in_sizes, int n_in,
                              void* d_out, int out_size, void* d_ws,
                              size_t ws_size, hipStream_t stream) {
  (void)in_sizes; (void)n_in; (void)out_size; (void)ws_size;
  const float* x = (const float*)d_in[0];
  const float* w_qkv = (const float*)d_in[1];
  const float* b_qkv = (const float*)d_in[2];
  const float* w_out = (const float*)d_in[3];
  const float* b_out = (const float*)d_in[4];
  float* outp = (float*)d_out;

  const size_t TENS = (size_t)B_ * N_ * C_;  // 4M elems
  u8* Qt = (u8*)d_ws;        // [B][N][C] fp8 (scaled)      4 MB
  u8* Kt = Qt + TENS;        // [B][N][C] fp8 (scaled)      4 MB
  u8* Vn = Kt + TENS;        // [B][C][N] fp8               4 MB
  u16* Op = (u16*)(Vn + TENS);  // [2][B][N][C] bf16       16 MB
  float* Ml = (float*)(Op + 2 * TENS);          // [4][B][N]  256 KB
  u16* Wqb = (u16*)(Ml + 4 * (size_t)B_ * N_);  // [3C][C]    384 KB
  u16* Wob = Wqb + 3 * C_ * C_;                 // [C][C]     128 KB

  k_prep<<<dim3(128), 256, 0, stream>>>(w_qkv, w_out, Wqb, Wob);
  k_qkv<<<dim3(64, 2, 4), 256, 0, stream>>>(Wqb, b_qkv, x, Qt, Kt, Vn);
  k_attn<<<dim3(256), 512, 0, stream>>>(Qt, Kt, Vn, Op, Ml);
  k_out<<<dim3(128, 4), 256, 0, stream>>>(Wob, b_out, x, outp, Op, Ml);
}